// Round 1
// baseline (3350.871 us; speedup 1.0000x reference)
//
#include <hip/hip_runtime.h>

// PolicyAwareLSTM: 2-layer LSTM (4096 x 336, 32->64->32) + seq1-MHA (== two 32x32
// matmuls) + dense 32->64->24 head. fp32 throughout (no fp32 MFMA on CDNA4).
//
// Design: one gate-column of W1/U1 per thread in REGISTERS (broadcast LDS reads of
// activations), split-K layer-2 columns across thread halves. 512 blocks x 8 rows,
// 256 threads, 2 blocks/CU.
//
// R1 change: amdgpu_waves_per_eu(2,2). Grid (512 blocks) caps residency at
// 2 blocks/CU = 2 waves/SIMD, so a 256-VGPR budget is free. Previously the
// allocator kept only 108 arch VGPRs (targeting unreachable occupancy) and the
// 144 loop-carried weight floats could not stay resident -> ~1 extra VALU op
// (accvgpr copy / remat reload) per FMA, matching VALUBusy=71.5% vs the ~35%
// the source arithmetic requires. Pinning waves/EU to exactly 2 lets all
// weights live in arch VGPRs.

#define B_TOTAL 4096
#define T_STEPS 336
#define NF      32     // input features
#define U1N     64     // layer-1 units
#define G1      256    // 4*U1N
#define U2N     32     // layer-2 units
#define G2      128    // 4*U2N
#define RROWS   8      // batch rows per block
#define NT      256    // threads per block

__device__ __forceinline__ float fast_sigmoid(float x) {
    return __fdividef(1.0f, 1.0f + __expf(-x));
}

__device__ __forceinline__ float fast_tanh(float x) {
    float ax = fabsf(x);
    float e  = __expf(-2.0f * ax);
    float r  = __fdividef(1.0f - e, 1.0f + e);
    return __builtin_copysignf(r, x);
}

__global__ __launch_bounds__(NT)
__attribute__((amdgpu_waves_per_eu(2, 2)))
void lstm_fused(
    const float* __restrict__ x,
    const float* __restrict__ W1, const float* __restrict__ U1, const float* __restrict__ b1,
    const float* __restrict__ W2, const float* __restrict__ U2, const float* __restrict__ b2,
    const float* __restrict__ Wv, const float* __restrict__ bv,
    const float* __restrict__ Wo, const float* __restrict__ bo,
    const float* __restrict__ Wd1, const float* __restrict__ bd1,
    const float* __restrict__ Wd2, const float* __restrict__ bd2,
    float* __restrict__ out)
{
    __shared__ float x_sh[2][RROWS][NF];      // double-buffered input slice
    __shared__ float h1_sh[RROWS][U1N];
    __shared__ float h2_sh[RROWS][U2N];
    __shared__ float z1_sh[RROWS][G1];
    __shared__ float z2p_sh[RROWS][2][G2];    // split-K partials for layer 2
    __shared__ float t0_sh[RROWS][U2N];       // head temp (v, then o)
    __shared__ float d1_sh[RROWS][64];        // head temp (dense1)

    const int tid = threadIdx.x;
    const int r0  = blockIdx.x * RROWS;

    // ---- load weight columns into registers (coalesced: lanes -> consecutive cols)
    float w1c[NF], u1c[U1N];
    #pragma unroll
    for (int j = 0; j < NF; ++j)  w1c[j] = W1[j * G1 + tid];
    #pragma unroll
    for (int j = 0; j < U1N; ++j) u1c[j] = U1[j * G1 + tid];
    const float b1r = b1[tid];

    const int g2   = tid & (G2 - 1);
    const int half = tid >> 7;                // 0: K-elems [0..32)/[0..16), 1: rest
    float w2c[32], u2c[16];
    #pragma unroll
    for (int j = 0; j < 32; ++j) w2c[j] = W2[(half * 32 + j) * G2 + g2];
    #pragma unroll
    for (int j = 0; j < 16; ++j) u2c[j] = U2[(half * 16 + j) * G2 + g2];
    const float b2r = (half == 0) ? b2[g2] : 0.0f;

    // ---- zero initial states
    ((float*)h1_sh)[tid]      = 0.0f;         // RROWS*U1N = 512
    ((float*)h1_sh)[NT + tid] = 0.0f;
    ((float*)h2_sh)[tid]      = 0.0f;         // RROWS*U2N = 256
    float c1a0 = 0.0f, c1a1 = 0.0f;           // cell state L1: 2 units/thread
    float c2a  = 0.0f;                        // cell state L2: 1 unit/thread

    // ---- preload x for t=0
    const int xr = tid >> 5, xj = tid & 31;   // 8 rows x 32 feats = 256 threads
    const int xbase = (r0 + xr) * (T_STEPS * NF) + xj;
    x_sh[0][xr][xj] = x[xbase];
    __syncthreads();

    for (int t = 0; t < T_STEPS; ++t) {
        const int buf = t & 1;

        // prefetch next step's x slice (clamped at the end; extra load is harmless)
        const int tn = (t + 1 < T_STEPS) ? (t + 1) : (T_STEPS - 1);
        const float xnext = x[xbase + tn * NF];

        // ---- phase 1: z1[r][tid] = b1 + x_t@W1 + h1@U1  (broadcast LDS reads)
        #pragma unroll
        for (int r = 0; r < RROWS; ++r) {
            float acc = b1r;
            #pragma unroll
            for (int j = 0; j < NF; ++j)  acc = fmaf(x_sh[buf][r][j], w1c[j], acc);
            #pragma unroll
            for (int j = 0; j < U1N; ++j) acc = fmaf(h1_sh[r][j], u1c[j], acc);
            z1_sh[r][tid] = acc;
        }
        __syncthreads();

        // ---- gate 1: 2 units per thread (Keras order i,f,g,o)
        {
            #pragma unroll
            for (int k = 0; k < 2; ++k) {
                const int flat = tid + k * NT;
                const int r = flat >> 6, u = flat & 63;
                const float zi = z1_sh[r][u];
                const float zf = z1_sh[r][64 + u];
                const float zg = z1_sh[r][128 + u];
                const float zo = z1_sh[r][192 + u];
                const float ig = fast_sigmoid(zi);
                const float fg = fast_sigmoid(zf);
                const float gg = fast_tanh(zg);
                const float og = fast_sigmoid(zo);
                float cprev = (k == 0) ? c1a0 : c1a1;
                const float c = fmaf(fg, cprev, ig * gg);
                if (k == 0) c1a0 = c; else c1a1 = c;
                h1_sh[r][u] = og * fast_tanh(c);
            }
        }
        __syncthreads();

        // ---- phase 2: z2 partials, split-K across thread halves
        #pragma unroll
        for (int r = 0; r < RROWS; ++r) {
            float acc = b2r;
            #pragma unroll
            for (int j = 0; j < 32; ++j) acc = fmaf(h1_sh[r][half * 32 + j], w2c[j], acc);
            #pragma unroll
            for (int j = 0; j < 16; ++j) acc = fmaf(h2_sh[r][half * 16 + j], u2c[j], acc);
            z2p_sh[r][half][g2] = acc;
        }
        __syncthreads();

        // ---- gate 2: 1 unit per thread
        {
            const int r = tid >> 5, u = tid & 31;
            const float zi = z2p_sh[r][0][u]      + z2p_sh[r][1][u];
            const float zf = z2p_sh[r][0][32 + u] + z2p_sh[r][1][32 + u];
            const float zg = z2p_sh[r][0][64 + u] + z2p_sh[r][1][64 + u];
            const float zo = z2p_sh[r][0][96 + u] + z2p_sh[r][1][96 + u];
            const float ig = fast_sigmoid(zi);
            const float fg = fast_sigmoid(zf);
            const float gg = fast_tanh(zg);
            const float og = fast_sigmoid(zo);
            c2a = fmaf(fg, c2a, ig * gg);
            h2_sh[r][u] = og * fast_tanh(c2a);
        }
        // park prefetched x into the other buffer (read was >=1 barrier ago)
        x_sh[1 - buf][xr][xj] = xnext;
        __syncthreads();
    }

    // ---- head: v = h2@Wv+bv ; o = v@Wo+bo ; d1 = relu(o@Wd1+bd1) ; out = d1@Wd2+bd2
    {
        const int r = tid >> 5, cidx = tid & 31;
        float acc = bv[cidx];
        #pragma unroll
        for (int j = 0; j < 32; ++j) acc = fmaf(h2_sh[r][j], Wv[j * 32 + cidx], acc);
        t0_sh[r][cidx] = acc;              // v
        __syncthreads();

        float acc2 = bo[cidx];
        #pragma unroll
        for (int j = 0; j < 32; ++j) acc2 = fmaf(t0_sh[r][j], Wo[j * 32 + cidx], acc2);
        __syncthreads();                   // all reads of v done
        t0_sh[r][cidx] = acc2;             // o
        __syncthreads();

        #pragma unroll
        for (int k = 0; k < 2; ++k) {
            const int c64 = cidx + k * 32;
            float a = bd1[c64];
            #pragma unroll
            for (int j = 0; j < 32; ++j) a = fmaf(t0_sh[r][j], Wd1[j * 64 + c64], a);
            d1_sh[r][c64] = fmaxf(a, 0.0f);
        }
        __syncthreads();

        if (tid < RROWS * 24) {
            const int rr = tid / 24, cc = tid - rr * 24;
            float a = bd2[cc];
            #pragma unroll
            for (int j = 0; j < 64; ++j) a = fmaf(d1_sh[rr][j], Wd2[j * 24 + cc], a);
            out[(r0 + rr) * 24 + cc] = a;
        }
    }
}

extern "C" void kernel_launch(void* const* d_in, const int* in_sizes, int n_in,
                              void* d_out, int out_size, void* d_ws, size_t ws_size,
                              hipStream_t stream) {
    const float* x   = (const float*)d_in[0];
    const float* W1  = (const float*)d_in[1];
    const float* U1  = (const float*)d_in[2];
    const float* b1  = (const float*)d_in[3];
    const float* W2  = (const float*)d_in[4];
    const float* U2  = (const float*)d_in[5];
    const float* b2  = (const float*)d_in[6];
    // d_in[7..10] = Wq, bq, Wk, bk — dead: softmax over a length-1 axis is identically 1
    const float* Wv  = (const float*)d_in[11];
    const float* bv  = (const float*)d_in[12];
    const float* Wo  = (const float*)d_in[13];
    const float* bo  = (const float*)d_in[14];
    const float* Wd1 = (const float*)d_in[15];
    const float* bd1 = (const float*)d_in[16];
    const float* Wd2 = (const float*)d_in[17];
    const float* bd2 = (const float*)d_in[18];
    float* outp = (float*)d_out;

    hipLaunchKernelGGL(lstm_fused, dim3(B_TOTAL / RROWS), dim3(NT), 0, stream,
                       x, W1, U1, b1, W2, U2, b2, Wv, bv, Wo, bo,
                       Wd1, bd1, Wd2, bd2, outp);
}

// Round 2
// 1933.502 us; speedup vs baseline: 1.7331x; 1.7331x over previous
//
#include <hip/hip_runtime.h>

// PolicyAwareLSTM: 2-layer LSTM (4096 x 336, 32->64->32) + seq1-MHA (== two 32x32
// matmuls) + dense 32->64->24 head. fp32 throughout (no fp32 MFMA on CDNA4).
//
// R2 restructure: 512 threads/block, 512 blocks (2 blocks/CU, 16 waves/CU).
//  - Per-thread weights: 48 (L1) + 24 (L2) floats (was 144) -> allocatable.
//  - Gate-interleaved 4-cols/thread + K-split: thread owns the 4 gates (i,f,g,o)
//    of ONE unit over a K-slice (12 for L1, 6 for L2). Each broadcast activation
//    read feeds 4 FMAs (was 1) -> 4x fewer LDS reads; partial z stores and gate
//    reduction reads are contiguous float4.
//  - Unified activation row act[x(32)|h1(64)|h2(32)]: L1 reads [0,96), L2 reads
//    [32,128), both contiguous & aligned. Single-buffered (barrier-protected).
//  - zp partial buffer (64KB) shared between layers and reused as head scratch.

#define B_TOTAL 4096
#define T_STEPS 336
#define NF      32     // input features
#define U1N     64     // layer-1 units
#define G1      256    // 4*U1N
#define U2N     32     // layer-2 units
#define G2      128    // 4*U2N
#define RROWS   8      // batch rows per block
#define NT      512    // threads per block
#define KH1     12     // L1 K-slice (8 k-groups x 12 = 96)
#define KG1     8
#define KH2     6      // L2 K-slice (16 k-groups x 6 = 96)
#define KG2     16

__device__ __forceinline__ float fast_sigmoid(float x) {
    return __fdividef(1.0f, 1.0f + __expf(-x));
}

__device__ __forceinline__ float fast_tanh(float x) {
    float ax = fabsf(x);
    float e  = __expf(-2.0f * ax);
    float r  = __fdividef(1.0f - e, 1.0f + e);
    return __builtin_copysignf(r, x);
}

__global__ __launch_bounds__(NT) void lstm_fused(
    const float* __restrict__ x,
    const float* __restrict__ W1, const float* __restrict__ U1, const float* __restrict__ b1,
    const float* __restrict__ W2, const float* __restrict__ U2, const float* __restrict__ b2,
    const float* __restrict__ Wv, const float* __restrict__ bv,
    const float* __restrict__ Wo, const float* __restrict__ bo,
    const float* __restrict__ Wd1, const float* __restrict__ bd1,
    const float* __restrict__ Wd2, const float* __restrict__ bd2,
    float* __restrict__ out)
{
    __shared__ float act_sh[RROWS][128];       // [x(32) | h1(64) | h2(32)] per row, 4KB
    __shared__ float zp[RROWS * KG1 * G1];     // 64KB: L1 partials [r][kg1][4u+g];
                                               // L2 partials [r][kg2][4u+g] (flat); head scratch

    const int tid = threadIdx.x;
    const int r0  = blockIdx.x * RROWS;

    // ---- thread roles
    const int ucol = tid & 63;                 // L1 unit (0..63)
    const int kg1  = tid >> 6;                 // L1 k-group (0..7)
    const int u2   = tid & 31;                 // L2 unit (0..31)
    const int kg2  = tid >> 5;                 // L2 k-group (0..15)
    const int g1r  = tid >> 6, g1u = tid & 63; // gate1 / d1 mapping (8r x 64u)
    const int g2r  = tid >> 5, g2u = tid & 31; // gate2 / x-park / head mapping (8r x 32u)

    // ---- weights: 4 gate-columns of one unit, K-sliced (load-time gather, coalesced in u)
    float4 w1w[KH1];
    #pragma unroll
    for (int j = 0; j < KH1; ++j) {
        const int kk = KH1 * kg1 + j;          // 0..95 over [x(32)|h1(64)]
        const float* row = (kk < NF) ? (W1 + kk * G1) : (U1 + (kk - NF) * G1);
        w1w[j] = make_float4(row[ucol], row[64 + ucol], row[128 + ucol], row[192 + ucol]);
    }
    float4 b1v = make_float4(0.f, 0.f, 0.f, 0.f);
    if (kg1 == 0)
        b1v = make_float4(b1[ucol], b1[64 + ucol], b1[128 + ucol], b1[192 + ucol]);

    float4 w2w[KH2];
    #pragma unroll
    for (int j = 0; j < KH2; ++j) {
        const int kk = KH2 * kg2 + j;          // 0..95 over [h1(64)|h2(32)]
        const float* row = (kk < U1N) ? (W2 + kk * G2) : (U2 + (kk - U1N) * G2);
        w2w[j] = make_float4(row[u2], row[32 + u2], row[64 + u2], row[96 + u2]);
    }
    float4 b2v = make_float4(0.f, 0.f, 0.f, 0.f);
    if (kg2 == 0)
        b2v = make_float4(b2[u2], b2[32 + u2], b2[64 + u2], b2[96 + u2]);

    // ---- init: zero act (x area overwritten below), zero cell states
    reinterpret_cast<float2*>(&act_sh[0][0])[tid] = make_float2(0.f, 0.f); // 1024 floats
    float c1 = 0.f, c2 = 0.f;

    const int xbase = (r0 + g2r) * (T_STEPS * NF) + g2u;   // x-park role: row g2r, feat g2u
    __syncthreads();
    if (tid < 256) act_sh[g2r][g2u] = x[xbase];            // x_0
    __syncthreads();

    for (int t = 0; t < T_STEPS; ++t) {
        // prefetch next x slice (issued early; parked after B1)
        float xnext = 0.f;
        if (tid < 256) {
            const int tn = (t + 1 < T_STEPS) ? (t + 1) : (T_STEPS - 1);
            xnext = x[xbase + tn * NF];
        }

        // ---- phase 1: z1 partials. Thread: unit ucol, gates i/f/g/o, k in [12*kg1, +12)
        {
            const int ab = KH1 * kg1;          // 16B-aligned (48B multiples)
            #pragma unroll
            for (int r = 0; r < RROWS; ++r) {
                const float4* av = reinterpret_cast<const float4*>(&act_sh[r][ab]);
                const float4 a0 = av[0], a1 = av[1], a2 = av[2];
                float a[KH1];
                a[0]=a0.x; a[1]=a0.y; a[2]=a0.z;  a[3]=a0.w;
                a[4]=a1.x; a[5]=a1.y; a[6]=a1.z;  a[7]=a1.w;
                a[8]=a2.x; a[9]=a2.y; a[10]=a2.z; a[11]=a2.w;
                float4 acc = b1v;
                #pragma unroll
                for (int j = 0; j < KH1; ++j) {
                    acc.x = fmaf(a[j], w1w[j].x, acc.x);
                    acc.y = fmaf(a[j], w1w[j].y, acc.y);
                    acc.z = fmaf(a[j], w1w[j].z, acc.z);
                    acc.w = fmaf(a[j], w1w[j].w, acc.w);
                }
                *reinterpret_cast<float4*>(&zp[(r * KG1 + kg1) * G1 + 4 * ucol]) = acc;
            }
        }
        __syncthreads();  // B1: zp(L1) ready; act reads of phase1 done

        // ---- gate 1: thread = (row g1r, unit g1u); sum 8 k-group partials (float4 reads)
        {
            float4 z = make_float4(0.f, 0.f, 0.f, 0.f);
            #pragma unroll
            for (int k = 0; k < KG1; ++k) {
                const float4 p = *reinterpret_cast<const float4*>(&zp[(g1r * KG1 + k) * G1 + 4 * g1u]);
                z.x += p.x; z.y += p.y; z.z += p.z; z.w += p.w;
            }
            const float ig = fast_sigmoid(z.x);
            const float fg = fast_sigmoid(z.y);
            const float gg = fast_tanh(z.z);
            const float og = fast_sigmoid(z.w);
            c1 = fmaf(fg, c1, ig * gg);
            act_sh[g1r][NF + g1u] = og * fast_tanh(c1);     // h1_t
            if (tid < 256) act_sh[g2r][g2u] = xnext;        // park x_{t+1}
        }
        __syncthreads();  // B2: h1_t visible; zp(L1) reads done

        // ---- phase 2: z2 partials. Thread: unit u2, k in act-coords [32+6*kg2, +6)
        {
            const int ab = NF + KH2 * kg2;     // 8B-aligned
            #pragma unroll
            for (int r = 0; r < RROWS; ++r) {
                const float2* av = reinterpret_cast<const float2*>(&act_sh[r][ab]);
                const float2 a0 = av[0], a1 = av[1], a2 = av[2];
                float a[KH2];
                a[0]=a0.x; a[1]=a0.y; a[2]=a1.x; a[3]=a1.y; a[4]=a2.x; a[5]=a2.y;
                float4 acc = b2v;
                #pragma unroll
                for (int j = 0; j < KH2; ++j) {
                    acc.x = fmaf(a[j], w2w[j].x, acc.x);
                    acc.y = fmaf(a[j], w2w[j].y, acc.y);
                    acc.z = fmaf(a[j], w2w[j].z, acc.z);
                    acc.w = fmaf(a[j], w2w[j].w, acc.w);
                }
                *reinterpret_cast<float4*>(&zp[(r * KG2 + kg2) * G2 + 4 * u2]) = acc;
            }
        }
        __syncthreads();  // B3: zp(L2) ready; act reads of phase2 done

        // ---- gate 2: tid<256 = (row g2r, unit g2u); sum 16 k-group partials
        if (tid < 256) {
            float4 z = make_float4(0.f, 0.f, 0.f, 0.f);
            #pragma unroll
            for (int k = 0; k < KG2; ++k) {
                const float4 p = *reinterpret_cast<const float4*>(&zp[(g2r * KG2 + k) * G2 + 4 * g2u]);
                z.x += p.x; z.y += p.y; z.z += p.z; z.w += p.w;
            }
            const float ig = fast_sigmoid(z.x);
            const float fg = fast_sigmoid(z.y);
            const float gg = fast_tanh(z.z);
            const float og = fast_sigmoid(z.w);
            c2 = fmaf(fg, c2, ig * gg);
            act_sh[g2r][96 + g2u] = og * fast_tanh(c2);     // h2_t
        }
        __syncthreads();  // B4: zp free for next phase1; h2_t visible
    }

    // ---- head: v = h2@Wv+bv ; o = v@Wo+bo ; d1 = relu(o@Wd1+bd1) ; out = d1@Wd2+bd2
    {
        float* hb = &zp[0];                    // scratch: v[0..256), o[256..512), d1[512..1024)
        if (tid < 256) {
            float acc = bv[g2u];
            #pragma unroll
            for (int j = 0; j < 32; ++j) acc = fmaf(act_sh[g2r][96 + j], Wv[j * 32 + g2u], acc);
            hb[tid] = acc;                     // v[r][u]
        }
        __syncthreads();
        if (tid < 256) {
            float acc = bo[g2u];
            #pragma unroll
            for (int j = 0; j < 32; ++j) acc = fmaf(hb[g2r * 32 + j], Wo[j * 32 + g2u], acc);
            hb[256 + tid] = acc;               // o[r][u]
        }
        __syncthreads();
        {
            // d1: all 512 threads, (row g1r, col g1u)
            float acc = bd1[g1u];
            #pragma unroll
            for (int j = 0; j < 32; ++j) acc = fmaf(hb[256 + g1r * 32 + j], Wd1[j * 64 + g1u], acc);
            hb[512 + tid] = fmaxf(acc, 0.f);   // d1[r][c]
        }
        __syncthreads();
        if (tid < RROWS * 24) {
            const int rr = tid / 24, cc = tid - rr * 24;
            float acc = bd2[cc];
            #pragma unroll
            for (int j = 0; j < 64; ++j) acc = fmaf(hb[512 + rr * 64 + j], Wd2[j * 24 + cc], acc);
            out[(r0 + rr) * 24 + cc] = acc;
        }
    }
}

extern "C" void kernel_launch(void* const* d_in, const int* in_sizes, int n_in,
                              void* d_out, int out_size, void* d_ws, size_t ws_size,
                              hipStream_t stream) {
    const float* x   = (const float*)d_in[0];
    const float* W1  = (const float*)d_in[1];
    const float* U1  = (const float*)d_in[2];
    const float* b1  = (const float*)d_in[3];
    const float* W2  = (const float*)d_in[4];
    const float* U2  = (const float*)d_in[5];
    const float* b2  = (const float*)d_in[6];
    // d_in[7..10] = Wq, bq, Wk, bk — dead: softmax over a length-1 axis is identically 1
    const float* Wv  = (const float*)d_in[11];
    const float* bv  = (const float*)d_in[12];
    const float* Wo  = (const float*)d_in[13];
    const float* bo  = (const float*)d_in[14];
    const float* Wd1 = (const float*)d_in[15];
    const float* bd1 = (const float*)d_in[16];
    const float* Wd2 = (const float*)d_in[17];
    const float* bd2 = (const float*)d_in[18];
    float* outp = (float*)d_out;

    hipLaunchKernelGGL(lstm_fused, dim3(B_TOTAL / RROWS), dim3(NT), 0, stream,
                       x, W1, U1, b1, W2, U2, b2, Wv, bv, Wo, bo,
                       Wd1, bd1, Wd2, bd2, outp);
}